// Round 12
// baseline (222.453 us; speedup 1.0000x reference)
//
#include <hip/hip_runtime.h>
#include <stdint.h>

typedef int int32x4 __attribute__((ext_vector_type(4)));

constexpr int K_DIM = 4096;   // D_IN
constexpr int N_DIM = 4096;   // D_OUT
constexpr float QMAXF = 127.0f;

// ---------------------------------------------------------------------------
// Kernel 1: per-token dynamic absmax quantization
// ---------------------------------------------------------------------------
__global__ __launch_bounds__(256) void quant_rows(const float* __restrict__ x,
                                                  int8_t* __restrict__ q,
                                                  float* __restrict__ scales) {
    const int row = blockIdx.x;
    const int tid = threadIdx.x;
    const size_t base = (size_t)row * K_DIM;

    const float4* xv = reinterpret_cast<const float4*>(x + base);
    float4 v[4];
#pragma unroll
    for (int i = 0; i < 4; ++i) v[i] = xv[tid + 256 * i];

    float m = 0.0f;
#pragma unroll
    for (int i = 0; i < 4; ++i)
        m = fmaxf(m, fmaxf(fmaxf(fabsf(v[i].x), fabsf(v[i].y)),
                           fmaxf(fabsf(v[i].z), fabsf(v[i].w))));
#pragma unroll
    for (int off = 32; off > 0; off >>= 1) m = fmaxf(m, __shfl_xor(m, off));

    __shared__ float wmax[4];
    if ((tid & 63) == 0) wmax[tid >> 6] = m;
    __syncthreads();
    const float am = fmaxf(fmaxf(wmax[0], wmax[1]), fmaxf(wmax[2], wmax[3]));
    const float scale = fmaxf(am * (1.0f / 127.0f), 1e-8f);
    if (tid == 0) scales[row] = scale;
    const float inv = 1.0f / scale;

    int* qw = reinterpret_cast<int*>(q + base);
#pragma unroll
    for (int i = 0; i < 4; ++i) {
        float f0 = fminf(QMAXF, fmaxf(-QMAXF, rintf(v[i].x * inv)));
        float f1 = fminf(QMAXF, fmaxf(-QMAXF, rintf(v[i].y * inv)));
        float f2 = fminf(QMAXF, fmaxf(-QMAXF, rintf(v[i].z * inv)));
        float f3 = fminf(QMAXF, fmaxf(-QMAXF, rintf(v[i].w * inv)));
        int b0 = ((int)f0) & 255, b1 = ((int)f1) & 255;
        int b2 = ((int)f2) & 255, b3 = ((int)f3) & 255;
        qw[tid + 256 * i] = b0 | (b1 << 8) | (b2 << 16) | (b3 << 24);
    }
}

// ---------------------------------------------------------------------------
// Kernel 2: pack int32 weight buffer -> int8
// ---------------------------------------------------------------------------
__global__ __launch_bounds__(256) void pack_w(const int* __restrict__ w,
                                              int8_t* __restrict__ w8) {
    const int idx = blockIdx.x * 256 + threadIdx.x;
    const int4 v = reinterpret_cast<const int4*>(w)[idx];
    int packed = (v.x & 255) | ((v.y & 255) << 8) | ((v.z & 255) << 16) | ((v.w & 255) << 24);
    reinterpret_cast<int*>(w8)[idx] = packed;
}

// ---------------------------------------------------------------------------
// Kernel 3: flatmm-v2 int8 GEMM. 256x256 tile, BKB=128, 8 waves (4M x 2N,
// wave tile 64x128), mfma_i32_16x16x64_i8.
//  - A: global->VGPR direct (no LDS). Load (mi,kh) = 16 rows x 64B contig
//    (16 full lines). Double-buffered across tiles, issued phases 0-3 of
//    the PREVIOUS tile -> >=4-phase lead over use.
//  - B: LDS ring-3 (96 KB), r6-exact layout+staging (measured 0 conflicts):
//    [row][8 slots x 16B], slot s of row r holds granule s^(r&7); staged via
//    pre-swizzled global source, linear LDS dest; GLL(t+2) at phase 4.
//  - vmcnt ledger (never drains in steady state): end-of-tile outstanding =
//    A(t+1)x8 then B(t+2)x4 -> vmcnt(4) drains A(t+1)+B(t+1), keeps B(t+2).
//    WAR: GLL(t+2)->slot (t-1)%3, whose reads finished before tile-t top
//    barrier; GLL issues after it.
//  - bf ping-pong: tile-top reads bf(ni=0); phase ni<7 reads bf(ni+1),
//    gate lgkmcnt(2); phase 7 gate lgkmcnt(0). sched_barrier after gates
//    (rule 18). 8 MFMA per phase.
// ---------------------------------------------------------------------------
constexpr int BM = 256, BN = 256, BKB = 128;
constexpr int NT = K_DIM / BKB;    // 32 K-tiles
constexpr int BSLOT = 32768;       // B ring slot bytes

#define GLL(src, dst)                                                          \
    __builtin_amdgcn_global_load_lds(                                          \
        (const __attribute__((address_space(1))) unsigned int*)(src),          \
        (__attribute__((address_space(3))) unsigned int*)(dst), 16, 0, 0)

#define MFMA_I8(a, b, c) __builtin_amdgcn_mfma_i32_16x16x64_i8((a), (b), (c), 0, 0, 0)

__global__ __launch_bounds__(512, 2) void w8a8_flat(
        const int8_t* __restrict__ A, const int8_t* __restrict__ B,
        const float* __restrict__ asc, const float* __restrict__ wsc,
        float* __restrict__ C, int M) {
    extern __shared__ int8_t lds[];   // 96 KB B ring

    const int tid  = threadIdx.x;
    const int lane = tid & 63;
    const int wave = tid >> 6;

    // XCD-aware bijective swizzle (nwg = 512, divisible by 8)
    const int nwg = gridDim.x;
    const int bid = blockIdx.x;
    const int swz = (bid & 7) * (nwg >> 3) + (bid >> 3);
    const int NB  = N_DIM / BN;               // 16
    const int brow = (swz / NB) * BM;
    const int bcol = (swz % NB) * BN;

    const int wm = wave & 3;                  // 0..3 (64-row quarter)
    const int wn = wave >> 2;                 // 0..1 (128-col half)
    const int l15 = lane & 15;
    const int ls  = lane >> 4;

    // ---- A direct-load base: row = brow + wm*64 + mi*16 + l15, k = ls*16 ----
    const int8_t* aglob = A + (size_t)(brow + wm * 64 + l15) * K_DIM + ls * 16;

    // ---- B staging (r6-exact): chunk c covers rows c*64 + (tid>>3) ----
    const int rowst = tid >> 3;                           // 0..63
    const int gsl   = ((tid & 7) ^ (rowst & 7)) * 16;     // swizzled granule
    const int8_t* gB = B + (size_t)(bcol + rowst) * K_DIM + gsl;
    const size_t chB = (size_t)64 * K_DIM;                // +64 rows
    const int segb = wave * 1024;                         // wave-uniform LDS base

    // ---- B compute-side swizzled offset (r6-exact mechanics) ----
    const int boff = (wn * 128 + l15) * BKB + ((ls ^ (l15 & 7)) * 16);
    // + ni*2048 ; kh=1 -> ^64 ; + slot*BSLOT

    int32x4 acc[4][8];
#pragma unroll
    for (int i = 0; i < 4; ++i)
#pragma unroll
        for (int j = 0; j < 8; ++j) acc[i][j] = (int32x4){0, 0, 0, 0};

    int32x4 avA[8], avB[8];

    // ---- prologue: A(0) loads, then B(0),B(1) GLL; vmcnt(4) keeps B(1) ----
#pragma unroll
    for (int mi = 0; mi < 4; ++mi) {
        avA[2 * mi]     = *(const int32x4*)(aglob + (size_t)mi * 16 * K_DIM);
        avA[2 * mi + 1] = *(const int32x4*)(aglob + (size_t)mi * 16 * K_DIM + 64);
    }
#pragma unroll
    for (int c = 0; c < 4; ++c) GLL(gB + c * chB, lds + c * 8192 + segb);
#pragma unroll
    for (int c = 0; c < 4; ++c) GLL(gB + 128 + c * chB, lds + BSLOT + c * 8192 + segb);
    asm volatile("s_waitcnt vmcnt(4)" ::: "memory");
    __builtin_amdgcn_s_barrier();

#define TILE_BODY(T, AVC, AVN)                                                 \
    {                                                                          \
        const int8_t* Bb = lds + ((T) % 3) * BSLOT;                            \
        const bool pf1 = ((T) + 1 < NT);                                       \
        const bool pf2 = ((T) + 2 < NT);                                       \
        int32x4 bf[2][2];                                                      \
        bf[0][0] = *(const int32x4*)(Bb + boff);                               \
        bf[0][1] = *(const int32x4*)(Bb + (boff ^ 64));                        \
        _Pragma("unroll")                                                      \
        for (int ni = 0; ni < 8; ++ni) {                                       \
            const int cur = ni & 1, nxt = cur ^ 1;                             \
            if (ni < 4 && pf1) {                                               \
                const int8_t* ap = aglob + ((T) + 1) * 128 +                   \
                                   (size_t)ni * 16 * K_DIM;                    \
                AVN[2 * ni]     = *(const int32x4*)(ap);                       \
                AVN[2 * ni + 1] = *(const int32x4*)(ap + 64);                  \
            }                                                                  \
            if (ni == 4 && pf2) {                                              \
                int8_t* dst = lds + (((T) + 2) % 3) * BSLOT;                   \
                _Pragma("unroll")                                              \
                for (int c = 0; c < 4; ++c)                                    \
                    GLL(gB + ((T) + 2) * 128 + c * chB,                        \
                        dst + c * 8192 + segb);                                \
            }                                                                  \
            if (ni < 7) {                                                      \
                const int o = boff + (ni + 1) * 2048;                          \
                bf[nxt][0] = *(const int32x4*)(Bb + o);                        \
                bf[nxt][1] = *(const int32x4*)(Bb + (o ^ 64));                 \
                asm volatile("s_waitcnt lgkmcnt(2)" ::: "memory");             \
            } else {                                                           \
                asm volatile("s_waitcnt lgkmcnt(0)" ::: "memory");             \
            }                                                                  \
            __builtin_amdgcn_sched_barrier(0);                                 \
            __builtin_amdgcn_s_setprio(1);                                     \
            _Pragma("unroll")                                                  \
            for (int mi = 0; mi < 4; ++mi) {                                   \
                acc[mi][ni] = MFMA_I8(AVC[2 * mi], bf[cur][0], acc[mi][ni]);   \
                acc[mi][ni] = MFMA_I8(AVC[2 * mi + 1], bf[cur][1], acc[mi][ni]); \
            }                                                                  \
            __builtin_amdgcn_s_setprio(0);                                     \
        }                                                                      \
        if ((T) <= NT - 3) asm volatile("s_waitcnt vmcnt(4)" ::: "memory");    \
        else               asm volatile("s_waitcnt vmcnt(0)" ::: "memory");    \
        __builtin_amdgcn_sched_barrier(0);                                     \
        __builtin_amdgcn_s_barrier();                                          \
    }

    for (int t = 0; t < NT; t += 2) {
        TILE_BODY(t,     avA, avB);
        TILE_BODY(t + 1, avB, avA);
    }

    // ---- epilogue: dequant + fp16-round; C/D: col=lane&15, row=(lane>>4)*4+reg
    const int c0  = lane & 15;
    const int rr0 = (lane >> 4) * 4;
#pragma unroll
    for (int ni = 0; ni < 8; ++ni) {
        const int col = bcol + wn * 128 + ni * 16 + c0;
        const float ws = wsc[col];
#pragma unroll
        for (int mi = 0; mi < 4; ++mi) {
            const int rowb = brow + wm * 64 + mi * 16 + rr0;
#pragma unroll
            for (int r = 0; r < 4; ++r) {
                const int row = rowb + r;
                float o = (float)acc[mi][ni][r] * asc[row] * ws;
                o = (float)(_Float16)o;   // emulate reference's fp16 cast
                C[(size_t)row * N_DIM + col] = o;
            }
        }
    }
}

// ---------------------------------------------------------------------------
extern "C" void kernel_launch(void* const* d_in, const int* in_sizes, int n_in,
                              void* d_out, int out_size, void* d_ws, size_t ws_size,
                              hipStream_t stream) {
    const float* x   = (const float*)d_in[0];   // [M][K], fp16-valued f32
    const int*   w   = (const int*)d_in[1];     // [N][K] int32 (int8-valued)
    const float* wsc = (const float*)d_in[2];   // [N]
    float* out = (float*)d_out;                 // [M][N] (fp16-valued f32)

    const int K = K_DIM;
    const int M = in_sizes[0] / K;              // 8192
    const int N = N_DIM;

    int8_t* q   = (int8_t*)d_ws;                               // M*K  = 32 MB
    int8_t* w8  = (int8_t*)d_ws + (size_t)M * K;               // N*K  = 16 MB
    float*  asc = (float*)((char*)d_ws + (size_t)M * K + (size_t)N * K);

    quant_rows<<<M, 256, 0, stream>>>(x, q, asc);
    pack_w<<<(N * (K / 4)) / 256, 256, 0, stream>>>(w, w8);
    const int grid = (M / BM) * (N / BN);       // 512
    w8a8_flat<<<grid, 512, 98304, stream>>>(q, w8, asc, wsc, out, M);
}

// Round 13
// 206.745 us; speedup vs baseline: 1.0760x; 1.0760x over previous
//
#include <hip/hip_runtime.h>
#include <stdint.h>

typedef int int32x4 __attribute__((ext_vector_type(4)));

constexpr int K_DIM = 4096;   // D_IN
constexpr int N_DIM = 4096;   // D_OUT
constexpr float QMAXF = 127.0f;

// ---------------------------------------------------------------------------
// Kernel 1: per-token absmax quant -> FRAGMENT-MAJOR q_t.
// q_t: panel p = row>>4; 1KB block (p,kq) at (p*64+kq)*1024 holds rows
// p*16..p*16+15, kbytes kq*64..+64; unit (ls,r15) at ls*256+r15*16 = bytes
// [kq*64+ls*16, +16) of row p*16+r15. So byte u*16 of panel = chunk
// (kq=u>>6, ls=(u>>4)&3, r15=u&15). One block = one 16-row panel.
// 2-pass (absmax then quantize); pass2 re-read hits L2/L3 (x fits 256MB L3).
// Transpose via LDS [16][4096+16pad].
// ---------------------------------------------------------------------------
__global__ __launch_bounds__(256) void quant_t(const float* __restrict__ x,
                                               int8_t* __restrict__ qt,
                                               float* __restrict__ scales) {
    __shared__ int8_t lq[16][4112];
    const int b = blockIdx.x;          // panel
    const int tid = threadIdx.x;
    const int row16 = tid >> 4;        // 0..15
    const int j = tid & 15;
    const size_t rbase = ((size_t)b * 16 + row16) * K_DIM;
    const float4* xr = reinterpret_cast<const float4*>(x + rbase);

    // pass 1: absmax. chunk c = j + 16*i covers float4s c*4..c*4+3
    float m = 0.0f;
#pragma unroll 4
    for (int i = 0; i < 16; ++i) {
        const int c = j + 16 * i;
#pragma unroll
        for (int s = 0; s < 4; ++s) {
            float4 v = xr[c * 4 + s];
            m = fmaxf(m, fmaxf(fmaxf(fabsf(v.x), fabsf(v.y)),
                               fmaxf(fabsf(v.z), fabsf(v.w))));
        }
    }
#pragma unroll
    for (int off = 8; off > 0; off >>= 1) m = fmaxf(m, __shfl_xor(m, off));
    const float scale = fmaxf(m * (1.0f / 127.0f), 1e-8f);
    if (j == 0) scales[b * 16 + row16] = scale;
    const float inv = 1.0f / scale;

    // pass 2: quantize chunk (16 int8) -> LDS[row16][c*16]
#pragma unroll 4
    for (int i = 0; i < 16; ++i) {
        const int c = j + 16 * i;
        int w[4];
#pragma unroll
        for (int s = 0; s < 4; ++s) {
            float4 v = xr[c * 4 + s];
            int b0 = ((int)fminf(QMAXF, fmaxf(-QMAXF, rintf(v.x * inv)))) & 255;
            int b1 = ((int)fminf(QMAXF, fmaxf(-QMAXF, rintf(v.y * inv)))) & 255;
            int b2 = ((int)fminf(QMAXF, fmaxf(-QMAXF, rintf(v.z * inv)))) & 255;
            int b3 = ((int)fminf(QMAXF, fmaxf(-QMAXF, rintf(v.w * inv)))) & 255;
            w[s] = b0 | (b1 << 8) | (b2 << 16) | (b3 << 24);
        }
        *reinterpret_cast<int32x4*>(&lq[row16][c * 16]) = (int32x4){w[0], w[1], w[2], w[3]};
    }
    __syncthreads();

    // write-out: unit u = tid + 256*i; global fully coalesced (1KB/wave)
    int8_t* outp = qt + (size_t)b * 65536;
#pragma unroll
    for (int i = 0; i < 16; ++i) {
        const int u = tid + 256 * i;
        int32x4 v = *reinterpret_cast<const int32x4*>(&lq[u & 15][(u >> 4) * 16]);
        *reinterpret_cast<int32x4*>(outp + (size_t)u * 16) = v;
    }
}

// ---------------------------------------------------------------------------
// Kernel 2: pack int32 weight buffer -> int8
// ---------------------------------------------------------------------------
__global__ __launch_bounds__(256) void pack_w(const int* __restrict__ w,
                                              int8_t* __restrict__ w8) {
    const int idx = blockIdx.x * 256 + threadIdx.x;
    const int4 v = reinterpret_cast<const int4*>(w)[idx];
    int packed = (v.x & 255) | ((v.y & 255) << 8) | ((v.z & 255) << 16) | ((v.w & 255) << 24);
    reinterpret_cast<int*>(w8)[idx] = packed;
}

// ---------------------------------------------------------------------------
// Kernel 3: flatmm-v3. r12 skeleton (passed) with A loads CONTIGUOUS from
// fragment-major q_t (the r12 fix: 16-line gather -> 1KB coalesced load).
// 256x256 tile, BKB=128, 8 waves (4M x 2N, wave tile 64x128), 16x16x64 MFMA.
//  - A: global->VGPR, frag (wm,mi,t,kh) = 1KB contiguous at
//    ((brow>>4 + wm*4 + mi)*64 + t*2 + kh)*1024 + lane*16. Dbuf across
//    tiles, 2 loads/phase at phases 0-3.
//  - B: LDS ring-3 (96 KB), r6-exact swizzle (0 conflicts), GLL(t+2) at ph4.
//  - vmcnt ledger: per tile issues (old->new) A(t+1)@ph0..3 (8), B(t+2)@ph4
//    (4). End-of-tile vmcnt(8) keeps newest 8 = {A ph7..5, B(t+2)x4, A ph4}:
//    B(t+1) (issued LAST tile's ph4, older) drained => next tile's B reads
//    safe after barrier; B(t+2) stays in flight (2-tile lead). Compiler
//    auto-waits cover A uses (it tracks GLL intrinsics in vmcnt).
//  - bf ping-pong reads + lgkmcnt(2) gates (r12-exact).
// ---------------------------------------------------------------------------
constexpr int BM = 256, BN = 256, BKB = 128;
constexpr int NT = K_DIM / BKB;    // 32 K-tiles
constexpr int BSLOT = 32768;       // B ring slot bytes

#define GLL(src, dst)                                                          \
    __builtin_amdgcn_global_load_lds(                                          \
        (const __attribute__((address_space(1))) unsigned int*)(src),          \
        (__attribute__((address_space(3))) unsigned int*)(dst), 16, 0, 0)

#define MFMA_I8(a, b, c) __builtin_amdgcn_mfma_i32_16x16x64_i8((a), (b), (c), 0, 0, 0)

__global__ __launch_bounds__(512, 2) void w8a8_flat(
        const int8_t* __restrict__ QT, const int8_t* __restrict__ B,
        const float* __restrict__ asc, const float* __restrict__ wsc,
        float* __restrict__ C, int M) {
    extern __shared__ int8_t lds[];   // 96 KB B ring

    const int tid  = threadIdx.x;
    const int lane = tid & 63;
    const int wave = tid >> 6;

    // XCD-aware bijective swizzle (nwg = 512, divisible by 8)
    const int nwg = gridDim.x;
    const int bid = blockIdx.x;
    const int swz = (bid & 7) * (nwg >> 3) + (bid >> 3);
    const int NB  = N_DIM / BN;               // 16
    const int brow = (swz / NB) * BM;
    const int bcol = (swz % NB) * BN;

    const int wm = wave & 3;                  // 0..3 (64-row quarter)
    const int wn = wave >> 2;                 // 0..1 (128-col half)
    const int l15 = lane & 15;
    const int ls  = lane >> 4;

    // ---- A fragment-major base: + ((wm*4+mi)*64 + t*2 + kh)*1024 ----
    const int8_t* qa = QT + (size_t)(brow >> 4) * 65536 + lane * 16;

    // ---- B staging (r6-exact, 0 conflicts) ----
    const int rowst = tid >> 3;                           // 0..63
    const int gsl   = ((tid & 7) ^ (rowst & 7)) * 16;     // swizzled granule
    const int8_t* gB = B + (size_t)(bcol + rowst) * K_DIM + gsl;
    const size_t chB = (size_t)64 * K_DIM;                // +64 rows
    const int segb = wave * 1024;                         // wave-uniform LDS base

    // ---- B compute-side swizzled offset (r6-exact) ----
    const int boff = (wn * 128 + l15) * BKB + ((ls ^ (l15 & 7)) * 16);
    // + ni*2048 ; kh=1 -> ^64 ; + slot*BSLOT

    int32x4 acc[4][8];
#pragma unroll
    for (int i = 0; i < 4; ++i)
#pragma unroll
        for (int j = 0; j < 8; ++j) acc[i][j] = (int32x4){0, 0, 0, 0};

    int32x4 avA[8], avB[8];

    // ---- prologue: A(0) frags, GLL B(0),B(1); vmcnt(4) keeps B(1) ----
#pragma unroll
    for (int mi = 0; mi < 4; ++mi) {
        const int8_t* ap = qa + (((wm * 4 + mi) * 64) << 10);
        avA[2 * mi]     = *(const int32x4*)(ap);
        avA[2 * mi + 1] = *(const int32x4*)(ap + 1024);
    }
#pragma unroll
    for (int c = 0; c < 4; ++c) GLL(gB + c * chB, lds + c * 8192 + segb);
#pragma unroll
    for (int c = 0; c < 4; ++c) GLL(gB + 128 + c * chB, lds + BSLOT + c * 8192 + segb);
    asm volatile("s_waitcnt vmcnt(4)" ::: "memory");   // B(0) landed
    __builtin_amdgcn_s_barrier();

#define TILE_BODY(T, AVC, AVN)                                                 \
    {                                                                          \
        const int8_t* Bb = lds + ((T) % 3) * BSLOT;                            \
        const bool pf1 = ((T) + 1 < NT);                                       \
        const bool pf2 = ((T) + 2 < NT);                                       \
        int32x4 bf[2][2];                                                      \
        bf[0][0] = *(const int32x4*)(Bb + boff);                               \
        bf[0][1] = *(const int32x4*)(Bb + (boff ^ 64));                        \
        _Pragma("unroll")                                                      \
        for (int ni = 0; ni < 8; ++ni) {                                       \
            const int cur = ni & 1, nxt = cur ^ 1;                             \
            if (ni < 4 && pf1) {                                               \
                const int8_t* ap = qa +                                        \
                    ((((wm * 4 + ni) * 64) + ((T) + 1) * 2) << 10);            \
                AVN[2 * ni]     = *(const int32x4*)(ap);                       \
                AVN[2 * ni + 1] = *(const int32x4*)(ap + 1024);                \
            }                                                                  \
            if (ni == 4 && pf2) {                                              \
                int8_t* dst = lds + (((T) + 2) % 3) * BSLOT;                   \
                _Pragma("unroll")                                              \
                for (int c = 0; c < 4; ++c)                                    \
                    GLL(gB + ((T) + 2) * 128 + c * chB,                        \
                        dst + c * 8192 + segb);                                \
            }                                                                  \
            if (ni < 7) {                                                      \
                const int o = boff + (ni + 1) * 2048;                          \
                bf[nxt][0] = *(const int32x4*)(Bb + o);                        \
                bf[nxt][1] = *(const int32x4*)(Bb + (o ^ 64));                 \
                asm volatile("s_waitcnt lgkmcnt(2)" ::: "memory");             \
            } else {                                                           \
                asm volatile("s_waitcnt lgkmcnt(0)" ::: "memory");             \
            }                                                                  \
            __builtin_amdgcn_sched_barrier(0);                                 \
            __builtin_amdgcn_s_setprio(1);                                     \
            _Pragma("unroll")                                                  \
            for (int mi = 0; mi < 4; ++mi) {                                   \
                acc[mi][ni] = MFMA_I8(AVC[2 * mi], bf[cur][0], acc[mi][ni]);   \
                acc[mi][ni] = MFMA_I8(AVC[2 * mi + 1], bf[cur][1], acc[mi][ni]); \
            }                                                                  \
            __builtin_amdgcn_s_setprio(0);                                     \
        }                                                                      \
        if ((T) < NT - 1) asm volatile("s_waitcnt vmcnt(8)" ::: "memory");     \
        else              asm volatile("s_waitcnt vmcnt(0)" ::: "memory");     \
        __builtin_amdgcn_sched_barrier(0);                                     \
        __builtin_amdgcn_s_barrier();                                          \
    }

    for (int t = 0; t < NT; t += 2) {
        TILE_BODY(t,     avA, avB);
        TILE_BODY(t + 1, avB, avA);
    }

    // ---- epilogue (r12-exact): col=lane&15, row=(lane>>4)*4+reg ----
    const int c0  = lane & 15;
    const int rr0 = (lane >> 4) * 4;
#pragma unroll
    for (int ni = 0; ni < 8; ++ni) {
        const int col = bcol + wn * 128 + ni * 16 + c0;
        const float ws = wsc[col];
#pragma unroll
        for (int mi = 0; mi < 4; ++mi) {
            const int rowb = brow + wm * 64 + mi * 16 + rr0;
#pragma unroll
            for (int r = 0; r < 4; ++r) {
                const int row = rowb + r;
                float o = (float)acc[mi][ni][r] * asc[row] * ws;
                o = (float)(_Float16)o;   // emulate reference's fp16 cast
                C[(size_t)row * N_DIM + col] = o;
            }
        }
    }
}

// ---------------------------------------------------------------------------
extern "C" void kernel_launch(void* const* d_in, const int* in_sizes, int n_in,
                              void* d_out, int out_size, void* d_ws, size_t ws_size,
                              hipStream_t stream) {
    const float* x   = (const float*)d_in[0];   // [M][K], fp16-valued f32
    const int*   w   = (const int*)d_in[1];     // [N][K] int32 (int8-valued)
    const float* wsc = (const float*)d_in[2];   // [N]
    float* out = (float*)d_out;                 // [M][N] (fp16-valued f32)

    const int K = K_DIM;
    const int M = in_sizes[0] / K;              // 8192
    const int N = N_DIM;

    int8_t* qt  = (int8_t*)d_ws;                               // M*K  = 32 MB
    int8_t* w8  = (int8_t*)d_ws + (size_t)M * K;               // N*K  = 16 MB
    float*  asc = (float*)((char*)d_ws + (size_t)M * K + (size_t)N * K);

    quant_t<<<M / 16, 256, 0, stream>>>(x, qt, asc);
    pack_w<<<(N * (K / 4)) / 256, 256, 0, stream>>>(w, w8);
    const int grid = (M / BM) * (N / BN);       // 512
    w8a8_flat<<<grid, 512, 98304, stream>>>(qt, w8, asc, wsc, out, M);
}